// Round 1
// 78.729 us; speedup vs baseline: 1.0143x; 1.0143x over previous
//
#include <hip/hip_runtime.h>

// IncidenceConvolution: the reference is an affine (no-activation) MLP on
// x = inc/S1, so weight(x) = A*x + C with A,C foldable from weights alone:
//   out[row] = A * S2 / S1^2 + C     (S1 = sum inc, S2 = sum inc^2)
//
// Single fused kernel (one block per row): each block redundantly folds the
// weights (8 KB, L1/L2-resident after first touch; ~4K FLOPs) while its
// row's HBM loads are in flight, then does the sum / sum-of-squares
// reduction. This removes the previous 1-block fold_kernel graph node that
// serialized (~3-5 us launch+latency) ahead of the reduction.

#define HID 32
#define L_LEN 2048
#define BLOCK 256

__global__ __launch_bounds__(BLOCK) void fused_kernel(
    const float* __restrict__ inc,
    const float* __restrict__ w1, const float* __restrict__ b1,
    const float* __restrict__ w2, const float* __restrict__ b2,
    const float* __restrict__ w3, const float* __restrict__ b3,
    const float* __restrict__ w4, const float* __restrict__ b4,
    float* __restrict__ out)
{
    const int row = blockIdx.x;          // 0 .. 2047
    const int tid = threadIdx.x;         // 0 .. 255

    __shared__ float s_v2[HID];
    __shared__ float s_c2[HID];
    __shared__ float s_AC[2];            // {A, C}
    __shared__ float s_partial[8];       // 4 waves x {s1, s2}

    // Issue the row loads FIRST: 256 threads x 2 float4 = 8 KB from HBM.
    // They are consumed only after the fold phase, so the HBM latency hides
    // under the (L2-resident) weight fold below.
    const float4* p = (const float4*)(inc + (size_t)row * L_LEN);
    const float4 v0 = p[tid];
    const float4 v1 = p[tid + BLOCK];

    // ---- fold phase (lanes 0-31 of wave 0; other waves pass through) ----
    if (tid < HID) {
        float v2 = 0.f, c2 = 0.f;
#pragma unroll
        for (int h = 0; h < HID; ++h) {
            const float w = w2[h * HID + tid];
            v2 += w1[h] * w;
            c2 += b1[h] * w;
        }
        s_v2[tid] = v2;
        s_c2[tid] = c2 + b2[tid];
    }
    __syncthreads();
    if (tid < HID) {
        float v3 = 0.f, c3 = 0.f;
#pragma unroll
        for (int h = 0; h < HID; ++h) {
            const float w = w3[h * HID + tid];
            v3 += s_v2[h] * w;
            c3 += s_c2[h] * w;
        }
        const float wk = w4[tid];
        float a = v3 * wk;
        float c = (c3 + b3[tid]) * wk;
#pragma unroll
        for (int off = 16; off > 0; off >>= 1) {
            a += __shfl_down(a, off, 64);
            c += __shfl_down(c, off, 64);
        }
        if (tid == 0) {
            s_AC[0] = a;              // A
            s_AC[1] = c + b4[0];      // C
        }
    }

    // ---- reduction phase: S1 = sum, S2 = sum of squares ----
    float s1 = ((v0.x + v0.y) + (v0.z + v0.w)) + ((v1.x + v1.y) + (v1.z + v1.w));
    float s2 = ((v0.x * v0.x + v0.y * v0.y) + (v0.z * v0.z + v0.w * v0.w))
             + ((v1.x * v1.x + v1.y * v1.y) + (v1.z * v1.z + v1.w * v1.w));

#pragma unroll
    for (int off = 32; off > 0; off >>= 1) {
        s1 += __shfl_down(s1, off, 64);
        s2 += __shfl_down(s2, off, 64);
    }
    const int wave = tid >> 6;
    const int lane = tid & 63;
    if (lane == 0) {
        s_partial[wave * 2 + 0] = s1;
        s_partial[wave * 2 + 1] = s2;
    }
    __syncthreads();   // also orders s_AC for the final read

    if (tid == 0) {
        const float S1 = (s_partial[0] + s_partial[2]) + (s_partial[4] + s_partial[6]);
        const float S2 = (s_partial[1] + s_partial[3]) + (s_partial[5] + s_partial[7]);
        out[row] = s_AC[0] * S2 / (S1 * S1) + s_AC[1];
    }
}

extern "C" void kernel_launch(void* const* d_in, const int* in_sizes, int n_in,
                              void* d_out, int out_size, void* d_ws, size_t ws_size,
                              hipStream_t stream) {
    const float* inc = (const float*)d_in[0];   // [64, 32, 2048]
    const float* w1  = (const float*)d_in[1];
    const float* b1  = (const float*)d_in[2];
    const float* w2  = (const float*)d_in[3];
    const float* b2  = (const float*)d_in[4];
    const float* w3  = (const float*)d_in[5];
    const float* b3  = (const float*)d_in[6];
    const float* w4  = (const float*)d_in[7];
    const float* b4  = (const float*)d_in[8];
    float* out = (float*)d_out;                 // [64, 32] = 2048 rows

    fused_kernel<<<out_size, BLOCK, 0, stream>>>(
        inc, w1, b1, w2, b2, w3, b3, w4, b4, out);
}